// Round 8
// baseline (306.717 us; speedup 1.0000x reference)
//
#include <hip/hip_runtime.h>
#include <hip/hip_bf16.h>
#include <cstdint>

#define HW 256
#define CH 64

typedef __attribute__((ext_vector_type(8))) short bf16x8;
typedef __attribute__((ext_vector_type(4))) float f32x4;

__device__ __forceinline__ float b2f(unsigned short u) {
    union { unsigned int i; float f; } c; c.i = ((unsigned int)u) << 16; return c.f;
}
__device__ __forceinline__ unsigned short f2b(float f) {
    __hip_bfloat16 h = __float2bfloat16(f);
    return *(unsigned short*)&h;
}
__device__ __forceinline__ void gload16(const void* g, void* l) {
    __builtin_amdgcn_global_load_lds(
        (const __attribute__((address_space(1))) void*)g,
        (__attribute__((address_space(3))) void*)l, 16, 0, 0);
}

// ---------------------------------------------------------------------------
// Kernel W: conv_w [co][ci][ky][kx] f32 -> wt[ky][kx][co][ci] bf16, with
// 16B-chunk XOR swizzle within each co-row: chunk j stored at j ^ (co&7).
// ---------------------------------------------------------------------------
__global__ void wt_kernel(const float* __restrict__ cw, unsigned short* __restrict__ wt) {
    int i = blockIdx.x * 256 + threadIdx.x;
    if (i >= 9 * 64 * 64) return;
    int e = i & 7, j = (i >> 3) & 7, co = (i >> 6) & 63, t9 = i >> 12;
    int ky = t9 / 3, kx = t9 - ky * 3;
    int ci = j * 8 + e;
    wt[t9 * 4096 + co * 64 + ((j ^ (co & 7)) * 8) + e] = f2b(cw[co * 576 + ci * 9 + ky * 3 + kx]);
}

// ---------------------------------------------------------------------------
// Kernel A1: offset conv (fp32-exact) -> offs [b][py][px][2] interleaved f32.
// Tile 32w x 16h, 256 threads, 2 px/thread. 4-ci groups x16, double-buffered
// fp32 LDS [4][18 rows][38] (21.9 KB), T14 issue/commit pipeline.
// grid 1024 (XCD-chunked: one image per XCD -> 4 blocks/CU schedulable).
// ---------------------------------------------------------------------------
__global__ __launch_bounds__(256, 4) void offset_conv_kernel(
    const float* __restrict__ x, const float* __restrict__ ow,
    const float* __restrict__ ob, float* __restrict__ offs)
{
    __shared__ __align__(16) float sg[2][4 * 18 * 38];   // 2 x 10944 B

    const int orig = blockIdx.x;
    const int lid = (orig & 7) * 128 + (orig >> 3);      // XCD k owns image k
    const int b = lid >> 7;
    const int tile = lid & 127;
    const int bx = tile & 7, by = tile >> 3;             // 8 x-tiles, 16 y-tiles
    const int x0 = bx * 32, y0 = by * 16;
    const int t = threadIdx.x;
    const int xo = t & 15, r = t >> 4;                   // x-pair, row
    const float* xb = x + (size_t)b * CH * HW * HW;

    // stage: 4ci x 18 rows x 18 float2 = 1296 words
    float rv[6][2];
    auto issue = [&](int g) {
        #pragma unroll
        for (int k = 0; k < 6; ++k) {
            int idx = k * 256 + t;
            rv[k][0] = 0.f; rv[k][1] = 0.f;
            if (idx < 1296) {
                int ci4 = idx / 324;
                int rem = idx - ci4 * 324;
                int ly = rem / 18, k2 = rem - ly * 18;
                int gy = y0 - 1 + ly, gx = x0 - 2 + 2 * k2;   // gx even
                bool ok = ((unsigned)gy < 256u) && ((unsigned)gx < 256u);
                int cy = min(max(gy, 0), 255), cx = min(max(gx, 0), 254);
                float2 v = *(const float2*)&xb[((size_t)(g * 4 + ci4) * HW + cy) * HW + cx];
                if (ok) { rv[k][0] = v.x; rv[k][1] = v.y; }
            }
        }
    };
    auto commit = [&](float* buf) {
        #pragma unroll
        for (int k = 0; k < 6; ++k) {
            int idx = k * 256 + t;
            if (idx < 1296) {
                int ci4 = idx / 324;
                int rem = idx - ci4 * 324;
                int ly = rem / 18, k2 = rem - ly * 18;
                *(float2*)&buf[ci4 * 684 + ly * 38 + 2 * k2] = make_float2(rv[k][0], rv[k][1]);
            }
        }
    };

    issue(0); commit(sg[0]);
    __syncthreads();

    float a0[2], a1[2];
    a0[0] = ob[0]; a0[1] = ob[0]; a1[0] = ob[1]; a1[1] = ob[1];

    for (int g = 0; g < 16; ++g) {
        if (g < 15) issue(g + 1);
        const float* buf = sg[g & 1];
        #pragma unroll
        for (int ci4 = 0; ci4 < 4; ++ci4) {
            int ci = g * 4 + ci4;
            const float* w0 = &ow[ci * 9];          // wave-uniform -> s_load
            const float* w1 = &ow[(CH + ci) * 9];
            const float* pb = buf + ci4 * 684 + 2 * xo;
            #pragma unroll
            for (int ky = 0; ky < 3; ++ky) {
                const float* row = pb + (r + ky) * 38;
                float2 qa = *(const float2*)row;        // floats 2xo, 2xo+1
                float2 qb = *(const float2*)(row + 2);  // floats 2xo+2, 2xo+3
                float qc = row[4];                       // float 2xo+4
                float wk0 = w0[ky * 3 + 0], wk1 = w0[ky * 3 + 1], wk2 = w0[ky * 3 + 2];
                float vk0 = w1[ky * 3 + 0], vk1 = w1[ky * 3 + 1], vk2 = w1[ky * 3 + 2];
                a0[0] = fmaf(qa.y, wk0, a0[0]); a0[0] = fmaf(qb.x, wk1, a0[0]); a0[0] = fmaf(qb.y, wk2, a0[0]);
                a1[0] = fmaf(qa.y, vk0, a1[0]); a1[0] = fmaf(qb.x, vk1, a1[0]); a1[0] = fmaf(qb.y, vk2, a1[0]);
                a0[1] = fmaf(qb.x, wk0, a0[1]); a0[1] = fmaf(qb.y, wk1, a0[1]); a0[1] = fmaf(qc,   wk2, a0[1]);
                a1[1] = fmaf(qb.x, vk0, a1[1]); a1[1] = fmaf(qb.y, vk1, a1[1]); a1[1] = fmaf(qc,   vk2, a1[1]);
            }
        }
        if (g < 15) { commit(sg[(g + 1) & 1]); __syncthreads(); }
    }

    const int py = y0 + r, px0 = x0 + 2 * xo;
    float4 o;
    o.x = tanhf(a0[0]) * 2.0f;
    o.y = tanhf(a1[0]) * 2.0f;
    o.z = tanhf(a0[1]) * 2.0f;
    o.w = tanhf(a1[1]) * 2.0f;
    *(float4*)&offs[(((size_t)b * HW + py) * HW + px0) * 2] = o;
}

// ---------------------------------------------------------------------------
// Kernel A2: bilinear warp. Tile 32w x 16h, 512 threads, 1 px/thread.
// |offset|<2 => taps in [x0-2,x0+34) x [y0-2,y0+18). bf16 LDS tile
// [8ci][20 rows][19 words] double-buffered = 24.3 KB. 8 ci-groups, T14 split.
// Thread accumulates its full 128B px line in pk[8] (32 VGPRs), then writes
// 8 x 16B back-to-back -> full-line L2 writes (no RMW amplification).
// grid 1024 (XCD-chunked), __launch_bounds__(512,4) caps VGPR at 128.
// Output: warped bf16 NHWC [b][y][x][ci], 16B chunk j stored at j^(px&7).
// ---------------------------------------------------------------------------
__global__ __launch_bounds__(512, 4) void warp_kernel(
    const float* __restrict__ x, const float* __restrict__ offs,
    unsigned short* __restrict__ warped)
{
    __shared__ __align__(16) unsigned int sx[2][8 * 20 * 19];   // 2 x 12160 B

    const int orig = blockIdx.x;
    const int lid = (orig & 7) * 128 + (orig >> 3);      // XCD k owns image k
    const int b = lid >> 7;
    const int tile = lid & 127;
    const int bx = tile & 7, by = tile >> 3;
    const int x0 = bx * 32, y0 = by * 16;
    const int t = threadIdx.x;
    const int tx = t & 31, ty = t >> 5;
    const int px = x0 + tx, py = y0 + ty;
    const float* xb = x + (size_t)b * CH * HW * HW;

    // ---- per-px tap setup (fp32-exact offsets)
    const float2 off = *(const float2*)&offs[(((size_t)b * HW + py) * HW + px) * 2];
    float ix = fminf(fmaxf((float)px + off.x, 0.f), 255.f);
    float iy = fminf(fmaxf((float)py + off.y, 0.f), 255.f);
    float fx0 = floorf(ix), fy0 = floorf(iy);
    float wx = ix - fx0, wy = iy - fy0;
    int lx0 = (int)fx0 - x0 + 2;    // in [0,34]
    int ly0 = (int)fy0 - y0 + 2;    // in [0,18]
    float w00 = (1.f - wx) * (1.f - wy), w01 = wx * (1.f - wy);
    float w10 = (1.f - wx) * wy,         w11 = wx * wy;
    // out-of-tile next-texel cases (x1i!=x0i+1 at image edge) carry weight 0;
    // staged halo is zero-padded, so pair/next-row reads are always safe.
    const int wbase = ly0 * 19 + (lx0 >> 1);
    const int sh = (lx0 & 1) * 16;

    // stage: 8ci x 20 rows x 18 float2 = 2880 words
    float rv[6][2];
    auto issue = [&](int g) {
        #pragma unroll
        for (int k = 0; k < 6; ++k) {
            int idx = k * 512 + t;
            rv[k][0] = 0.f; rv[k][1] = 0.f;
            if (idx < 2880) {
                int ci8 = idx / 360;
                int rem = idx - ci8 * 360;
                int ly = rem / 18, k2 = rem - ly * 18;
                int gy = y0 - 2 + ly, gx = x0 - 2 + 2 * k2;   // gx even
                bool ok = ((unsigned)gy < 256u) && ((unsigned)gx < 256u);
                int cy = min(max(gy, 0), 255), cx = min(max(gx, 0), 254);
                float2 v = *(const float2*)&xb[((size_t)(g * 8 + ci8) * HW + cy) * HW + cx];
                if (ok) { rv[k][0] = v.x; rv[k][1] = v.y; }
            }
        }
    };
    auto commit = [&](unsigned int* buf) {
        #pragma unroll
        for (int k = 0; k < 6; ++k) {
            int idx = k * 512 + t;
            if (idx < 2880) {
                int ci8 = idx / 360;
                int rem = idx - ci8 * 360;
                int ly = rem / 18, k2 = rem - ly * 18;
                buf[ci8 * 380 + ly * 19 + k2] =
                    (unsigned int)f2b(rv[k][0]) | ((unsigned int)f2b(rv[k][1]) << 16);
            }
        }
    };

    issue(0); commit(sx[0]);
    __syncthreads();

    uint4 pk[8];
    #pragma unroll
    for (int g = 0; g < 8; ++g) {
        if (g < 7) issue(g + 1);
        const unsigned int* S = sx[g & 1];
        unsigned int res[4];
        #pragma unroll
        for (int p = 0; p < 4; ++p) {
            unsigned int pw = 0;
            #pragma unroll
            for (int h = 0; h < 2; ++h) {
                int base = (p * 2 + h) * 380 + wbase;
                unsigned long long ra =
                    ((unsigned long long)S[base + 1] << 32) | (unsigned long long)S[base];
                ra >>= sh;
                unsigned long long rb =
                    ((unsigned long long)S[base + 20] << 32) | (unsigned long long)S[base + 19];
                rb >>= sh;
                float v = b2f((unsigned short)ra) * w00 +
                          b2f((unsigned short)(ra >> 16)) * w01 +
                          b2f((unsigned short)rb) * w10 +
                          b2f((unsigned short)(rb >> 16)) * w11;
                pw |= ((unsigned int)f2b(v)) << (16 * h);
            }
            res[p] = pw;
        }
        pk[g] = make_uint4(res[0], res[1], res[2], res[3]);
        if (g < 7) { commit(sx[(g + 1) & 1]); __syncthreads(); }
    }

    unsigned short* wbp = warped + ((size_t)b * (HW * HW) + (size_t)py * HW + px) * CH;
    const int key = px & 7;
    #pragma unroll
    for (int g = 0; g < 8; ++g)
        *(uint4*)&wbp[(size_t)((g ^ key) * 8)] = pk[g];
}

// ---------------------------------------------------------------------------
// Kernel B: dilated(12) 3x3 conv 64->64 + BN + ReLU via bf16 MFMA implicit GEMM
// block = 256 threads (4 waves), computes 64co x 256px (one full output row).
// grid 2048 (XCD-chunked: XCD k = batch k -> oy,oy±12 rows reuse in its L2)
// ---------------------------------------------------------------------------
__global__ __launch_bounds__(256, 2) void conv_mfma_kernel(
    const unsigned short* __restrict__ warped, const unsigned short* __restrict__ wtb,
    const float* __restrict__ gamma, const float* __restrict__ beta,
    const float* __restrict__ mean, const float* __restrict__ var,
    float* __restrict__ out)
{
    __shared__ __align__(16) unsigned short sa[280 * 64];    // act row + 12px halos
    __shared__ __align__(16) unsigned short sw[3 * 64 * 64]; // weights for one ky
    __shared__ float sinv[64], sbias[64];

    const int t = threadIdx.x;
    const int orig = blockIdx.x;
    const int lid = (orig & 7) * 256 + (orig >> 3);
    const int oy = lid & 255, b = lid >> 8;
    const int wid = t >> 6, lane = t & 63;
    const int l15 = lane & 15, l4 = lane >> 4;

    if (t < 64) {
        float inv = gamma[t] * rsqrtf(var[t] + 1e-5f);
        sinv[t] = inv;
        sbias[t] = beta[t] - mean[t] * inv;
    }
    if (t < 192) {
        int p = t >> 3, sub = t & 7;
        int px = (p < 12) ? p : (256 + p);
        *(uint4*)&sa[px * 64 + sub * 8] = make_uint4(0, 0, 0, 0);
    }

    f32x4 acc[4][4];
    #pragma unroll
    for (int m = 0; m < 4; ++m)
        #pragma unroll
        for (int n = 0; n < 4; ++n) acc[m][n] = (f32x4){0.f, 0.f, 0.f, 0.f};

    const size_t bbase = (size_t)b * (HW * (size_t)HW * CH);

    for (int ky = 0; ky < 3; ++ky) {
        __syncthreads();
        int gy = oy + (ky - 1) * 12;
        if (gy >= 0 && gy < HW) {
            const char* src = (const char*)(warped + bbase + (size_t)gy * (HW * CH));
            #pragma unroll
            for (int r = 0; r < 8; ++r)
                gload16(src + r * 4096 + t * 16,
                        (char*)sa + 1536 + r * 4096 + wid * 1024);
        } else {
            #pragma unroll
            for (int r = 0; r < 8; ++r)
                *(uint4*)((char*)sa + 1536 + r * 4096 + t * 16) = make_uint4(0, 0, 0, 0);
        }
        {
            const char* wsrc = (const char*)wtb + ky * 24576;
            #pragma unroll
            for (int r = 0; r < 6; ++r)
                gload16(wsrc + r * 4096 + t * 16,
                        (char*)sw + r * 4096 + wid * 1024);
        }
        asm volatile("s_waitcnt vmcnt(0)" ::: "memory");
        __syncthreads();

        #pragma unroll
        for (int kx = 0; kx < 3; ++kx) {
            #pragma unroll
            for (int ks = 0; ks < 2; ++ks) {
                const int jg = ks * 4 + l4;
                bf16x8 af[4], bfr[4];
                #pragma unroll
                for (int m = 0; m < 4; ++m) {
                    int co = m * 16 + l15;
                    int jp = jg ^ (co & 7);
                    af[m] = *(const bf16x8*)&sw[(kx * 64 + co) * 64 + jp * 8];
                }
                #pragma unroll
                for (int n = 0; n < 4; ++n) {
                    int pl = wid * 64 + n * 16 + l15 + kx * 12;
                    int c = jg ^ ((pl + 4) & 7);
                    bfr[n] = *(const bf16x8*)&sa[pl * 64 + c * 8];
                }
                #pragma unroll
                for (int m = 0; m < 4; ++m)
                    #pragma unroll
                    for (int n = 0; n < 4; ++n)
                        acc[m][n] = __builtin_amdgcn_mfma_f32_16x16x32_bf16(
                            af[m], bfr[n], acc[m][n], 0, 0, 0);
            }
        }
    }

    #pragma unroll
    for (int m = 0; m < 4; ++m) {
        #pragma unroll
        for (int r = 0; r < 4; ++r) {
            int co = m * 16 + l4 * 4 + r;
            float inv = sinv[co], bs = sbias[co];
            float* orow = out + (((size_t)b * CH + co) * HW + oy) * HW + wid * 64 + l15;
            #pragma unroll
            for (int n = 0; n < 4; ++n)
                orow[n * 16] = fmaxf(fmaf(acc[m][n][r], inv, bs), 0.f);
        }
    }
}

extern "C" void kernel_launch(void* const* d_in, const int* in_sizes, int n_in,
                              void* d_out, int out_size, void* d_ws, size_t ws_size,
                              hipStream_t stream) {
    const float* x     = (const float*)d_in[0];
    const float* ow    = (const float*)d_in[1];
    const float* ob    = (const float*)d_in[2];
    const float* cw    = (const float*)d_in[3];
    const float* gamma = (const float*)d_in[4];
    const float* beta  = (const float*)d_in[5];
    const float* mean  = (const float*)d_in[6];
    const float* var   = (const float*)d_in[7];
    float* out = (float*)d_out;

    unsigned short* warped = (unsigned short*)d_ws;                       // 64 MB
    unsigned short* wtb    = (unsigned short*)((char*)d_ws + 67108864);   // 72 KB
    float*          offsb  = (float*)((char*)d_ws + 67108864 + 73728);    // 4.2 MB

    wt_kernel<<<(9 * 64 * 64 + 255) / 256, 256, 0, stream>>>(cw, wtb);

    offset_conv_kernel<<<dim3(1024), 256, 0, stream>>>(x, ow, ob, offsb);

    warp_kernel<<<dim3(1024), 512, 0, stream>>>(x, offsb, warped);

    conv_mfma_kernel<<<dim3(2048), 256, 0, stream>>>(warped, wtb, gamma, beta, mean, var, out);
}

// Round 9
// 270.344 us; speedup vs baseline: 1.1345x; 1.1345x over previous
//
#include <hip/hip_runtime.h>
#include <hip/hip_bf16.h>
#include <cstdint>

#define HW 256
#define CH 64

typedef __attribute__((ext_vector_type(8))) short bf16x8;
typedef __attribute__((ext_vector_type(4))) float f32x4;

__device__ __forceinline__ float b2f(unsigned short u) {
    union { unsigned int i; float f; } c; c.i = ((unsigned int)u) << 16; return c.f;
}
__device__ __forceinline__ unsigned short f2b(float f) {
    __hip_bfloat16 h = __float2bfloat16(f);
    return *(unsigned short*)&h;
}
__device__ __forceinline__ void gload16(const void* g, void* l) {
    __builtin_amdgcn_global_load_lds(
        (const __attribute__((address_space(1))) void*)g,
        (__attribute__((address_space(3))) void*)l, 16, 0, 0);
}

// ---------------------------------------------------------------------------
// Kernel W: conv_w [co][ci][ky][kx] f32 -> wt[ky][kx][co][ci] bf16, with
// 16B-chunk XOR swizzle within each co-row: chunk j stored at j ^ (co&7).
// ---------------------------------------------------------------------------
__global__ void wt_kernel(const float* __restrict__ cw, unsigned short* __restrict__ wt) {
    int i = blockIdx.x * 256 + threadIdx.x;
    if (i >= 9 * 64 * 64) return;
    int e = i & 7, j = (i >> 3) & 7, co = (i >> 6) & 63, t9 = i >> 12;
    int ky = t9 / 3, kx = t9 - ky * 3;
    int ci = j * 8 + e;
    wt[t9 * 4096 + co * 64 + ((j ^ (co & 7)) * 8) + e] = f2b(cw[co * 576 + ci * 9 + ky * 3 + kx]);
}

// ---------------------------------------------------------------------------
// Kernel A1: offset conv (fp32-exact) -> offs [b][py][px][2] interleaved f32.
// Tile 32w x 16h, 256 threads, 2 px/thread. 4-ci groups x16, double-buffered
// fp32 LDS [4][18 rows][38] (21.9 KB), T14 issue/commit pipeline.
// grid 1024 (XCD-chunked: one image per XCD).
// ---------------------------------------------------------------------------
__global__ __launch_bounds__(256, 4) void offset_conv_kernel(
    const float* __restrict__ x, const float* __restrict__ ow,
    const float* __restrict__ ob, float* __restrict__ offs)
{
    __shared__ __align__(16) float sg[2][4 * 18 * 38];   // 2 x 10944 B

    const int orig = blockIdx.x;
    const int lid = (orig & 7) * 128 + (orig >> 3);      // XCD k owns image k
    const int b = lid >> 7;
    const int tile = lid & 127;
    const int bx = tile & 7, by = tile >> 3;             // 8 x-tiles, 16 y-tiles
    const int x0 = bx * 32, y0 = by * 16;
    const int t = threadIdx.x;
    const int xo = t & 15, r = t >> 4;                   // x-pair, row
    const float* xb = x + (size_t)b * CH * HW * HW;

    // stage: 4ci x 18 rows x 18 float2 = 1296 words
    float rv[6][2];
    auto issue = [&](int g) {
        #pragma unroll
        for (int k = 0; k < 6; ++k) {
            int idx = k * 256 + t;
            rv[k][0] = 0.f; rv[k][1] = 0.f;
            if (idx < 1296) {
                int ci4 = idx / 324;
                int rem = idx - ci4 * 324;
                int ly = rem / 18, k2 = rem - ly * 18;
                int gy = y0 - 1 + ly, gx = x0 - 2 + 2 * k2;   // gx even
                bool ok = ((unsigned)gy < 256u) && ((unsigned)gx < 256u);
                int cy = min(max(gy, 0), 255), cx = min(max(gx, 0), 254);
                float2 v = *(const float2*)&xb[((size_t)(g * 4 + ci4) * HW + cy) * HW + cx];
                if (ok) { rv[k][0] = v.x; rv[k][1] = v.y; }
            }
        }
    };
    auto commit = [&](float* buf) {
        #pragma unroll
        for (int k = 0; k < 6; ++k) {
            int idx = k * 256 + t;
            if (idx < 1296) {
                int ci4 = idx / 324;
                int rem = idx - ci4 * 324;
                int ly = rem / 18, k2 = rem - ly * 18;
                *(float2*)&buf[ci4 * 684 + ly * 38 + 2 * k2] = make_float2(rv[k][0], rv[k][1]);
            }
        }
    };

    issue(0); commit(sg[0]);
    __syncthreads();

    float a0[2], a1[2];
    a0[0] = ob[0]; a0[1] = ob[0]; a1[0] = ob[1]; a1[1] = ob[1];

    for (int g = 0; g < 16; ++g) {
        if (g < 15) issue(g + 1);
        const float* buf = sg[g & 1];
        #pragma unroll
        for (int ci4 = 0; ci4 < 4; ++ci4) {
            int ci = g * 4 + ci4;
            const float* w0 = &ow[ci * 9];          // wave-uniform -> s_load
            const float* w1 = &ow[(CH + ci) * 9];
            const float* pb = buf + ci4 * 684 + 2 * xo;
            #pragma unroll
            for (int ky = 0; ky < 3; ++ky) {
                const float* row = pb + (r + ky) * 38;
                float2 qa = *(const float2*)row;
                float2 qb = *(const float2*)(row + 2);
                float qc = row[4];
                float wk0 = w0[ky * 3 + 0], wk1 = w0[ky * 3 + 1], wk2 = w0[ky * 3 + 2];
                float vk0 = w1[ky * 3 + 0], vk1 = w1[ky * 3 + 1], vk2 = w1[ky * 3 + 2];
                a0[0] = fmaf(qa.y, wk0, a0[0]); a0[0] = fmaf(qb.x, wk1, a0[0]); a0[0] = fmaf(qb.y, wk2, a0[0]);
                a1[0] = fmaf(qa.y, vk0, a1[0]); a1[0] = fmaf(qb.x, vk1, a1[0]); a1[0] = fmaf(qb.y, vk2, a1[0]);
                a0[1] = fmaf(qb.x, wk0, a0[1]); a0[1] = fmaf(qb.y, wk1, a0[1]); a0[1] = fmaf(qc,   wk2, a0[1]);
                a1[1] = fmaf(qb.x, vk0, a1[1]); a1[1] = fmaf(qb.y, vk1, a1[1]); a1[1] = fmaf(qc,   vk2, a1[1]);
            }
        }
        if (g < 15) { commit(sg[(g + 1) & 1]); __syncthreads(); }
    }

    const int py = y0 + r, px0 = x0 + 2 * xo;
    float4 o;
    o.x = tanhf(a0[0]) * 2.0f;
    o.y = tanhf(a1[0]) * 2.0f;
    o.z = tanhf(a0[1]) * 2.0f;
    o.w = tanhf(a1[1]) * 2.0f;
    *(float4*)&offs[(((size_t)b * HW + py) * HW + px0) * 2] = o;
}

// ---------------------------------------------------------------------------
// Kernel A2: bilinear warp. Tile 32w x 16h, 512 threads, 1 px/thread.
// bf16 LDS staging [8ci][20 rows][19 words] double-buffered (24.3 KB) carved
// from a 32 KB block shared with the store-redistribution image.
// Gather accumulates the px's 8 swizzled chunks in pk[8]; epilogue
// redistributes through LDS (2 half-passes of 8 rows) so every global store
// instruction is a contiguous 1KB wave run (full 64B sectors -> no RMW/partial
// -granule write amplification).
// grid 1024 (XCD-chunked). Output: warped bf16 NHWC, chunk j at j^(px&7).
// ---------------------------------------------------------------------------
__global__ __launch_bounds__(512, 4) void warp_kernel(
    const float* __restrict__ x, const float* __restrict__ offs,
    unsigned short* __restrict__ warped)
{
    __shared__ __align__(16) unsigned int smem[8192];   // 32 KB

    const int orig = blockIdx.x;
    const int lid = (orig & 7) * 128 + (orig >> 3);      // XCD k owns image k
    const int b = lid >> 7;
    const int tile = lid & 127;
    const int bx = tile & 7, by = tile >> 3;
    const int x0 = bx * 32, y0 = by * 16;
    const int t = threadIdx.x;
    const int tx = t & 31, ty = t >> 5;
    const int px = x0 + tx, py = y0 + ty;
    const float* xb = x + (size_t)b * CH * HW * HW;
    const int key = px & 7;

    // ---- per-px tap setup (fp32-exact offsets)
    const float2 off = *(const float2*)&offs[(((size_t)b * HW + py) * HW + px) * 2];
    float ix = fminf(fmaxf((float)px + off.x, 0.f), 255.f);
    float iy = fminf(fmaxf((float)py + off.y, 0.f), 255.f);
    float fx0 = floorf(ix), fy0 = floorf(iy);
    float wx = ix - fx0, wy = iy - fy0;
    int lx0 = (int)fx0 - x0 + 2;    // in [0,34]
    int ly0 = (int)fy0 - y0 + 2;    // in [0,18]
    float w00 = (1.f - wx) * (1.f - wy), w01 = wx * (1.f - wy);
    float w10 = (1.f - wx) * wy,         w11 = wx * wy;
    const int wbase = ly0 * 19 + (lx0 >> 1);
    const int sh = (lx0 & 1) * 16;

    // stage: 8ci x 20 rows x 19 words (38 shorts = lx 0..37; covers lx0+1<=35
    // and the word-18 tap; beyond-image gx clamps to 0 via ok=false)
    float rv[6][2];
    auto issue = [&](int g) {
        #pragma unroll
        for (int k = 0; k < 6; ++k) {
            int idx = k * 512 + t;
            rv[k][0] = 0.f; rv[k][1] = 0.f;
            if (idx < 3040) {
                int ci8 = idx / 380;
                int rem = idx - ci8 * 380;
                int ly = rem / 19, k2 = rem - ly * 19;
                int gy = y0 - 2 + ly, gx = x0 - 2 + 2 * k2;   // gx even
                bool ok = ((unsigned)gy < 256u) && ((unsigned)gx < 256u);
                int cy = min(max(gy, 0), 255), cx = min(max(gx, 0), 254);
                float2 v = *(const float2*)&xb[((size_t)(g * 8 + ci8) * HW + cy) * HW + cx];
                if (ok) { rv[k][0] = v.x; rv[k][1] = v.y; }
            }
        }
    };
    auto commit = [&](unsigned int* buf) {
        #pragma unroll
        for (int k = 0; k < 6; ++k) {
            int idx = k * 512 + t;
            if (idx < 3040) {
                int ci8 = idx / 380;
                int rem = idx - ci8 * 380;
                int ly = rem / 19, k2 = rem - ly * 19;
                buf[ci8 * 380 + ly * 19 + k2] =
                    (unsigned int)f2b(rv[k][0]) | ((unsigned int)f2b(rv[k][1]) << 16);
            }
        }
    };

    issue(0); commit(smem);
    __syncthreads();

    uint4 pk[8];
    #pragma unroll
    for (int g = 0; g < 8; ++g) {
        if (g < 7) issue(g + 1);
        const unsigned int* S = smem + (g & 1) * 3040;
        unsigned int res[4];
        #pragma unroll
        for (int p = 0; p < 4; ++p) {
            unsigned int pw = 0;
            #pragma unroll
            for (int h = 0; h < 2; ++h) {
                int base = (p * 2 + h) * 380 + wbase;
                unsigned long long ra =
                    ((unsigned long long)S[base + 1] << 32) | (unsigned long long)S[base];
                ra >>= sh;
                unsigned long long rb =
                    ((unsigned long long)S[base + 20] << 32) | (unsigned long long)S[base + 19];
                rb >>= sh;
                float v = b2f((unsigned short)ra) * w00 +
                          b2f((unsigned short)(ra >> 16)) * w01 +
                          b2f((unsigned short)rb) * w10 +
                          b2f((unsigned short)(rb >> 16)) * w11;
                pw |= ((unsigned int)f2b(v)) << (16 * h);
            }
            res[p] = pw;
        }
        pk[g] = make_uint4(res[0], res[1], res[2], res[3]);
        if (g < 7) { commit(smem + ((g + 1) & 1) * 3040); __syncthreads(); }
    }

    // ---- epilogue: redistribute through LDS, store contiguous 1KB wave runs
    for (int half = 0; half < 2; ++half) {
        __syncthreads();                       // previous smem use complete
        if ((ty >> 3) == half) {               // wave-uniform predicate
            const int rl = ty & 7;
            unsigned int* dst = smem + rl * 1024 + tx * 32;
            #pragma unroll
            for (int g = 0; g < 8; ++g)
                *(uint4*)&dst[(g ^ key) * 4] = pk[g];
        }
        __syncthreads();
        #pragma unroll
        for (int s = 0; s < 4; ++s) {
            int idx = s * 512 + t;             // 0..2047 over 8 rows x 256 chunks
            int r = idx >> 8, c = idx & 255;
            uint4 q = *(const uint4*)(smem + r * 1024 + c * 4);
            unsigned short* grow = warped +
                ((size_t)b * (HW * HW) + (size_t)(y0 + half * 8 + r) * HW + x0) * CH;
            *(uint4*)&grow[c * 8] = q;
        }
    }
}

// ---------------------------------------------------------------------------
// Kernel B: dilated(12) 3x3 conv 64->64 + BN + ReLU via bf16 MFMA implicit GEMM
// block = 256 threads (4 waves), computes 64co x 256px (one full output row).
// grid 2048 (XCD-chunked: XCD k = batch k -> oy,oy±12 rows reuse in its L2)
// ---------------------------------------------------------------------------
__global__ __launch_bounds__(256, 2) void conv_mfma_kernel(
    const unsigned short* __restrict__ warped, const unsigned short* __restrict__ wtb,
    const float* __restrict__ gamma, const float* __restrict__ beta,
    const float* __restrict__ mean, const float* __restrict__ var,
    float* __restrict__ out)
{
    __shared__ __align__(16) unsigned short sa[280 * 64];    // act row + 12px halos
    __shared__ __align__(16) unsigned short sw[3 * 64 * 64]; // weights for one ky
    __shared__ float sinv[64], sbias[64];

    const int t = threadIdx.x;
    const int orig = blockIdx.x;
    const int lid = (orig & 7) * 256 + (orig >> 3);
    const int oy = lid & 255, b = lid >> 8;
    const int wid = t >> 6, lane = t & 63;
    const int l15 = lane & 15, l4 = lane >> 4;

    if (t < 64) {
        float inv = gamma[t] * rsqrtf(var[t] + 1e-5f);
        sinv[t] = inv;
        sbias[t] = beta[t] - mean[t] * inv;
    }
    if (t < 192) {
        int p = t >> 3, sub = t & 7;
        int px = (p < 12) ? p : (256 + p);
        *(uint4*)&sa[px * 64 + sub * 8] = make_uint4(0, 0, 0, 0);
    }

    f32x4 acc[4][4];
    #pragma unroll
    for (int m = 0; m < 4; ++m)
        #pragma unroll
        for (int n = 0; n < 4; ++n) acc[m][n] = (f32x4){0.f, 0.f, 0.f, 0.f};

    const size_t bbase = (size_t)b * (HW * (size_t)HW * CH);

    for (int ky = 0; ky < 3; ++ky) {
        __syncthreads();
        int gy = oy + (ky - 1) * 12;
        if (gy >= 0 && gy < HW) {
            const char* src = (const char*)(warped + bbase + (size_t)gy * (HW * CH));
            #pragma unroll
            for (int r = 0; r < 8; ++r)
                gload16(src + r * 4096 + t * 16,
                        (char*)sa + 1536 + r * 4096 + wid * 1024);
        } else {
            #pragma unroll
            for (int r = 0; r < 8; ++r)
                *(uint4*)((char*)sa + 1536 + r * 4096 + t * 16) = make_uint4(0, 0, 0, 0);
        }
        {
            const char* wsrc = (const char*)wtb + ky * 24576;
            #pragma unroll
            for (int r = 0; r < 6; ++r)
                gload16(wsrc + r * 4096 + t * 16,
                        (char*)sw + r * 4096 + wid * 1024);
        }
        asm volatile("s_waitcnt vmcnt(0)" ::: "memory");
        __syncthreads();

        #pragma unroll
        for (int kx = 0; kx < 3; ++kx) {
            #pragma unroll
            for (int ks = 0; ks < 2; ++ks) {
                const int jg = ks * 4 + l4;
                bf16x8 af[4], bfr[4];
                #pragma unroll
                for (int m = 0; m < 4; ++m) {
                    int co = m * 16 + l15;
                    int jp = jg ^ (co & 7);
                    af[m] = *(const bf16x8*)&sw[(kx * 64 + co) * 64 + jp * 8];
                }
                #pragma unroll
                for (int n = 0; n < 4; ++n) {
                    int pl = wid * 64 + n * 16 + l15 + kx * 12;
                    int c = jg ^ ((pl + 4) & 7);
                    bfr[n] = *(const bf16x8*)&sa[pl * 64 + c * 8];
                }
                #pragma unroll
                for (int m = 0; m < 4; ++m)
                    #pragma unroll
                    for (int n = 0; n < 4; ++n)
                        acc[m][n] = __builtin_amdgcn_mfma_f32_16x16x32_bf16(
                            af[m], bfr[n], acc[m][n], 0, 0, 0);
            }
        }
    }

    #pragma unroll
    for (int m = 0; m < 4; ++m) {
        #pragma unroll
        for (int r = 0; r < 4; ++r) {
            int co = m * 16 + l4 * 4 + r;
            float inv = sinv[co], bs = sbias[co];
            float* orow = out + (((size_t)b * CH + co) * HW + oy) * HW + wid * 64 + l15;
            #pragma unroll
            for (int n = 0; n < 4; ++n)
                orow[n * 16] = fmaxf(fmaf(acc[m][n][r], inv, bs), 0.f);
        }
    }
}

extern "C" void kernel_launch(void* const* d_in, const int* in_sizes, int n_in,
                              void* d_out, int out_size, void* d_ws, size_t ws_size,
                              hipStream_t stream) {
    const float* x     = (const float*)d_in[0];
    const float* ow    = (const float*)d_in[1];
    const float* ob    = (const float*)d_in[2];
    const float* cw    = (const float*)d_in[3];
    const float* gamma = (const float*)d_in[4];
    const float* beta  = (const float*)d_in[5];
    const float* mean  = (const float*)d_in[6];
    const float* var   = (const float*)d_in[7];
    float* out = (float*)d_out;

    unsigned short* warped = (unsigned short*)d_ws;                       // 64 MB
    unsigned short* wtb    = (unsigned short*)((char*)d_ws + 67108864);   // 72 KB
    float*          offsb  = (float*)((char*)d_ws + 67108864 + 73728);    // 4.2 MB

    wt_kernel<<<(9 * 64 * 64 + 255) / 256, 256, 0, stream>>>(cw, wtb);

    offset_conv_kernel<<<dim3(1024), 256, 0, stream>>>(x, ow, ob, offsb);

    warp_kernel<<<dim3(1024), 512, 0, stream>>>(x, offsb, warped);

    conv_mfma_kernel<<<dim3(2048), 256, 0, stream>>>(warped, wtb, gamma, beta, mean, var, out);
}

// Round 11
// 250.387 us; speedup vs baseline: 1.2250x; 1.0797x over previous
//
#include <hip/hip_runtime.h>
#include <hip/hip_bf16.h>
#include <cstdint>

#define HW 256
#define CH 64

typedef __attribute__((ext_vector_type(8))) short bf16x8;
typedef __attribute__((ext_vector_type(4))) float f32x4;
typedef __attribute__((ext_vector_type(4))) unsigned int u32x4;

__device__ __forceinline__ float b2f(unsigned short u) {
    union { unsigned int i; float f; } c; c.i = ((unsigned int)u) << 16; return c.f;
}
__device__ __forceinline__ unsigned short f2b(float f) {
    __hip_bfloat16 h = __float2bfloat16(f);
    return *(unsigned short*)&h;
}
__device__ __forceinline__ void gload16(const void* g, void* l) {
    __builtin_amdgcn_global_load_lds(
        (const __attribute__((address_space(1))) void*)g,
        (__attribute__((address_space(3))) void*)l, 16, 0, 0);
}

// ---------------------------------------------------------------------------
// Kernel W: conv_w [co][ci][ky][kx] f32 -> wt[ky][kx][co][ci] bf16, with
// 16B-chunk XOR swizzle within each co-row: chunk j stored at j ^ (co&7).
// ---------------------------------------------------------------------------
__global__ void wt_kernel(const float* __restrict__ cw, unsigned short* __restrict__ wt) {
    int i = blockIdx.x * 256 + threadIdx.x;
    if (i >= 9 * 64 * 64) return;
    int e = i & 7, j = (i >> 3) & 7, co = (i >> 6) & 63, t9 = i >> 12;
    int ky = t9 / 3, kx = t9 - ky * 3;
    int ci = j * 8 + e;
    wt[t9 * 4096 + co * 64 + ((j ^ (co & 7)) * 8) + e] = f2b(cw[co * 576 + ci * 9 + ky * 3 + kx]);
}

// ---------------------------------------------------------------------------
// Kernel A1: offset conv (fp32-exact) -> offs [b][py][px][2] interleaved f32.
// Tile 32w x 8h, 256 threads, 1 px/thread. 4-ci groups x16, double-buffered
// fp32 LDS [4][10 rows][40] (12.8 KB dbuf), T14 issue/commit pipeline.
// grid 2048 (XCD-chunked) -> ~6 blocks/CU resident, latency well hidden.
// ---------------------------------------------------------------------------
__global__ __launch_bounds__(256, 6) void offset_conv_kernel(
    const float* __restrict__ x, const float* __restrict__ ow,
    const float* __restrict__ ob, float* __restrict__ offs)
{
    __shared__ __align__(16) float sg[2][4 * 10 * 40];   // 2 x 6400 B

    const int orig = blockIdx.x;
    const int lid = (orig & 7) * 256 + (orig >> 3);      // XCD k owns image k
    const int b = lid >> 8;
    const int tile = lid & 255;
    const int bx = tile & 7, by = tile >> 3;             // 8 x-tiles, 32 y-tiles
    const int x0 = bx * 32, y0 = by * 8;
    const int t = threadIdx.x;
    const int tx = t & 31, r = t >> 5;                   // px-in-tile, row
    const float* xb = x + (size_t)b * CH * HW * HW;

    // stage: 4ci x 10 rows x 19 float2 = 760 words
    float rv[3][2];
    auto issue = [&](int g) {
        #pragma unroll
        for (int k = 0; k < 3; ++k) {
            int idx = k * 256 + t;
            rv[k][0] = 0.f; rv[k][1] = 0.f;
            if (idx < 760) {
                int ci4 = idx / 190;
                int rem = idx - ci4 * 190;
                int ly = rem / 19, k2 = rem - ly * 19;
                int gy = y0 - 1 + ly, gx = x0 - 2 + 2 * k2;   // gx even
                bool ok = ((unsigned)gy < 256u) && ((unsigned)gx < 256u);
                int cy = min(max(gy, 0), 255), cx = min(max(gx, 0), 254);
                float2 v = *(const float2*)&xb[((size_t)(g * 4 + ci4) * HW + cy) * HW + cx];
                if (ok) { rv[k][0] = v.x; rv[k][1] = v.y; }
            }
        }
    };
    auto commit = [&](float* buf) {
        #pragma unroll
        for (int k = 0; k < 3; ++k) {
            int idx = k * 256 + t;
            if (idx < 760) {
                int ci4 = idx / 190;
                int rem = idx - ci4 * 190;
                int ly = rem / 19, k2 = rem - ly * 19;
                *(float2*)&buf[ci4 * 400 + ly * 40 + 2 * k2] = make_float2(rv[k][0], rv[k][1]);
            }
        }
    };

    issue(0); commit(sg[0]);
    __syncthreads();

    float a0 = ob[0], a1 = ob[1];
    const int par = (tx + 1) & 1;
    const int ebase = (tx + 1) & ~1;

    for (int g = 0; g < 16; ++g) {
        if (g < 15) issue(g + 1);
        const float* buf = sg[g & 1];
        #pragma unroll
        for (int ci4 = 0; ci4 < 4; ++ci4) {
            int ci = g * 4 + ci4;
            const float* w0 = &ow[ci * 9];          // wave-uniform -> s_load
            const float* w1 = &ow[(CH + ci) * 9];
            const float* pb = buf + ci4 * 400 + ebase;
            #pragma unroll
            for (int ky = 0; ky < 3; ++ky) {
                const float* row = pb + (r + ky) * 40;
                float2 qa = *(const float2*)row;
                float2 qb = *(const float2*)(row + 2);
                float t0 = par ? qa.y : qa.x;
                float t1 = par ? qb.x : qa.y;
                float t2 = par ? qb.y : qb.x;
                a0 = fmaf(t0, w0[ky * 3 + 0], a0);
                a1 = fmaf(t0, w1[ky * 3 + 0], a1);
                a0 = fmaf(t1, w0[ky * 3 + 1], a0);
                a1 = fmaf(t1, w1[ky * 3 + 1], a1);
                a0 = fmaf(t2, w0[ky * 3 + 2], a0);
                a1 = fmaf(t2, w1[ky * 3 + 2], a1);
            }
        }
        if (g < 15) { commit(sg[(g + 1) & 1]); __syncthreads(); }
    }

    const int py = y0 + r, px = x0 + tx;
    float2 o;
    o.x = tanhf(a0) * 2.0f;
    o.y = tanhf(a1) * 2.0f;
    *(float2*)&offs[(((size_t)b * HW + py) * HW + px) * 2] = o;
}

// ---------------------------------------------------------------------------
// Kernel A2: bilinear warp. Tile 32w x 16h, 512 threads, 1 px/thread.
// bf16 LDS staging [8ci][20 rows][19 words] double-buffered (24.3 KB) carved
// from a 32 KB block shared with the store-redistribution image.
// Epilogue redistributes through LDS then stores contiguous 1KB wave runs
// with NONTEMPORAL stores (warped is written once, read once by conv_mfma —
// no reason to hold it dirty in L2; tests the write-amplification anomaly).
// grid 1024 (XCD-chunked). Output: warped bf16 NHWC, chunk j at j^(px&7).
// ---------------------------------------------------------------------------
__global__ __launch_bounds__(512, 4) void warp_kernel(
    const float* __restrict__ x, const float* __restrict__ offs,
    unsigned short* __restrict__ warped)
{
    __shared__ __align__(16) unsigned int smem[8192];   // 32 KB

    const int orig = blockIdx.x;
    const int lid = (orig & 7) * 128 + (orig >> 3);      // XCD k owns image k
    const int b = lid >> 7;
    const int tile = lid & 127;
    const int bx = tile & 7, by = tile >> 3;
    const int x0 = bx * 32, y0 = by * 16;
    const int t = threadIdx.x;
    const int tx = t & 31, ty = t >> 5;
    const int px = x0 + tx, py = y0 + ty;
    const float* xb = x + (size_t)b * CH * HW * HW;
    const int key = px & 7;

    // ---- per-px tap setup (fp32-exact offsets)
    const float2 off = *(const float2*)&offs[(((size_t)b * HW + py) * HW + px) * 2];
    float ix = fminf(fmaxf((float)px + off.x, 0.f), 255.f);
    float iy = fminf(fmaxf((float)py + off.y, 0.f), 255.f);
    float fx0 = floorf(ix), fy0 = floorf(iy);
    float wx = ix - fx0, wy = iy - fy0;
    int lx0 = (int)fx0 - x0 + 2;    // in [0,34]
    int ly0 = (int)fy0 - y0 + 2;    // in [0,18]
    float w00 = (1.f - wx) * (1.f - wy), w01 = wx * (1.f - wy);
    float w10 = (1.f - wx) * wy,         w11 = wx * wy;
    const int wbase = ly0 * 19 + (lx0 >> 1);
    const int sh = (lx0 & 1) * 16;

    // stage: 8ci x 20 rows x 19 words
    float rv[6][2];
    auto issue = [&](int g) {
        #pragma unroll
        for (int k = 0; k < 6; ++k) {
            int idx = k * 512 + t;
            rv[k][0] = 0.f; rv[k][1] = 0.f;
            if (idx < 3040) {
                int ci8 = idx / 380;
                int rem = idx - ci8 * 380;
                int ly = rem / 19, k2 = rem - ly * 19;
                int gy = y0 - 2 + ly, gx = x0 - 2 + 2 * k2;   // gx even
                bool ok = ((unsigned)gy < 256u) && ((unsigned)gx < 256u);
                int cy = min(max(gy, 0), 255), cx = min(max(gx, 0), 254);
                float2 v = *(const float2*)&xb[((size_t)(g * 8 + ci8) * HW + cy) * HW + cx];
                if (ok) { rv[k][0] = v.x; rv[k][1] = v.y; }
            }
        }
    };
    auto commit = [&](unsigned int* buf) {
        #pragma unroll
        for (int k = 0; k < 6; ++k) {
            int idx = k * 512 + t;
            if (idx < 3040) {
                int ci8 = idx / 380;
                int rem = idx - ci8 * 380;
                int ly = rem / 19, k2 = rem - ly * 19;
                buf[ci8 * 380 + ly * 19 + k2] =
                    (unsigned int)f2b(rv[k][0]) | ((unsigned int)f2b(rv[k][1]) << 16);
            }
        }
    };

    issue(0); commit(smem);
    __syncthreads();

    u32x4 pk[8];
    #pragma unroll
    for (int g = 0; g < 8; ++g) {
        if (g < 7) issue(g + 1);
        const unsigned int* S = smem + (g & 1) * 3040;
        unsigned int res[4];
        #pragma unroll
        for (int p = 0; p < 4; ++p) {
            unsigned int pw = 0;
            #pragma unroll
            for (int h = 0; h < 2; ++h) {
                int base = (p * 2 + h) * 380 + wbase;
                unsigned long long ra =
                    ((unsigned long long)S[base + 1] << 32) | (unsigned long long)S[base];
                ra >>= sh;
                unsigned long long rb =
                    ((unsigned long long)S[base + 20] << 32) | (unsigned long long)S[base + 19];
                rb >>= sh;
                float v = b2f((unsigned short)ra) * w00 +
                          b2f((unsigned short)(ra >> 16)) * w01 +
                          b2f((unsigned short)rb) * w10 +
                          b2f((unsigned short)(rb >> 16)) * w11;
                pw |= ((unsigned int)f2b(v)) << (16 * h);
            }
            res[p] = pw;
        }
        pk[g] = (u32x4){res[0], res[1], res[2], res[3]};
        if (g < 7) { commit(smem + ((g + 1) & 1) * 3040); __syncthreads(); }
    }

    // ---- epilogue: redistribute through LDS, nontemporal contiguous stores
    for (int half = 0; half < 2; ++half) {
        __syncthreads();                       // previous smem use complete
        if ((ty >> 3) == half) {               // wave-uniform predicate
            const int rl = ty & 7;
            unsigned int* dst = smem + rl * 1024 + tx * 32;
            #pragma unroll
            for (int g = 0; g < 8; ++g)
                *(u32x4*)&dst[(g ^ key) * 4] = pk[g];
        }
        __syncthreads();
        #pragma unroll
        for (int s = 0; s < 4; ++s) {
            int idx = s * 512 + t;             // 0..2047 over 8 rows x 256 chunks
            int r = idx >> 8, c = idx & 255;
            u32x4 q = *(const u32x4*)(smem + r * 1024 + c * 4);
            unsigned short* grow = warped +
                ((size_t)b * (HW * HW) + (size_t)(y0 + half * 8 + r) * HW + x0) * CH;
            __builtin_nontemporal_store(q, (u32x4*)&grow[c * 8]);
        }
    }
}

// ---------------------------------------------------------------------------
// Kernel B: dilated(12) 3x3 conv 64->64 + BN + ReLU via bf16 MFMA implicit GEMM
// block = 256 threads (4 waves), computes 64co x 256px (one full output row).
// grid 2048 (XCD-chunked). Output stores nontemporal (write-once, never read).
// ---------------------------------------------------------------------------
__global__ __launch_bounds__(256, 2) void conv_mfma_kernel(
    const unsigned short* __restrict__ warped, const unsigned short* __restrict__ wtb,
    const float* __restrict__ gamma, const float* __restrict__ beta,
    const float* __restrict__ mean, const float* __restrict__ var,
    float* __restrict__ out)
{
    __shared__ __align__(16) unsigned short sa[280 * 64];    // act row + 12px halos
    __shared__ __align__(16) unsigned short sw[3 * 64 * 64]; // weights for one ky
    __shared__ float sinv[64], sbias[64];

    const int t = threadIdx.x;
    const int orig = blockIdx.x;
    const int lid = (orig & 7) * 256 + (orig >> 3);
    const int oy = lid & 255, b = lid >> 8;
    const int wid = t >> 6, lane = t & 63;
    const int l15 = lane & 15, l4 = lane >> 4;

    if (t < 64) {
        float inv = gamma[t] * rsqrtf(var[t] + 1e-5f);
        sinv[t] = inv;
        sbias[t] = beta[t] - mean[t] * inv;
    }
    if (t < 192) {
        int p = t >> 3, sub = t & 7;
        int px = (p < 12) ? p : (256 + p);
        *(uint4*)&sa[px * 64 + sub * 8] = make_uint4(0, 0, 0, 0);
    }

    f32x4 acc[4][4];
    #pragma unroll
    for (int m = 0; m < 4; ++m)
        #pragma unroll
        for (int n = 0; n < 4; ++n) acc[m][n] = (f32x4){0.f, 0.f, 0.f, 0.f};

    const size_t bbase = (size_t)b * (HW * (size_t)HW * CH);

    for (int ky = 0; ky < 3; ++ky) {
        __syncthreads();
        int gy = oy + (ky - 1) * 12;
        if (gy >= 0 && gy < HW) {
            const char* src = (const char*)(warped + bbase + (size_t)gy * (HW * CH));
            #pragma unroll
            for (int r = 0; r < 8; ++r)
                gload16(src + r * 4096 + t * 16,
                        (char*)sa + 1536 + r * 4096 + wid * 1024);
        } else {
            #pragma unroll
            for (int r = 0; r < 8; ++r)
                *(uint4*)((char*)sa + 1536 + r * 4096 + t * 16) = make_uint4(0, 0, 0, 0);
        }
        {
            const char* wsrc = (const char*)wtb + ky * 24576;
            #pragma unroll
            for (int r = 0; r < 6; ++r)
                gload16(wsrc + r * 4096 + t * 16,
                        (char*)sw + r * 4096 + wid * 1024);
        }
        asm volatile("s_waitcnt vmcnt(0)" ::: "memory");
        __syncthreads();

        #pragma unroll
        for (int kx = 0; kx < 3; ++kx) {
            #pragma unroll
            for (int ks = 0; ks < 2; ++ks) {
                const int jg = ks * 4 + l4;
                bf16x8 af[4], bfr[4];
                #pragma unroll
                for (int m = 0; m < 4; ++m) {
                    int co = m * 16 + l15;
                    int jp = jg ^ (co & 7);
                    af[m] = *(const bf16x8*)&sw[(kx * 64 + co) * 64 + jp * 8];
                }
                #pragma unroll
                for (int n = 0; n < 4; ++n) {
                    int pl = wid * 64 + n * 16 + l15 + kx * 12;
                    int c = jg ^ ((pl + 4) & 7);
                    bfr[n] = *(const bf16x8*)&sa[pl * 64 + c * 8];
                }
                #pragma unroll
                for (int m = 0; m < 4; ++m)
                    #pragma unroll
                    for (int n = 0; n < 4; ++n)
                        acc[m][n] = __builtin_amdgcn_mfma_f32_16x16x32_bf16(
                            af[m], bfr[n], acc[m][n], 0, 0, 0);
            }
        }
    }

    #pragma unroll
    for (int m = 0; m < 4; ++m) {
        #pragma unroll
        for (int r = 0; r < 4; ++r) {
            int co = m * 16 + l4 * 4 + r;
            float inv = sinv[co], bs = sbias[co];
            float* orow = out + (((size_t)b * CH + co) * HW + oy) * HW + wid * 64 + l15;
            #pragma unroll
            for (int n = 0; n < 4; ++n)
                __builtin_nontemporal_store(
                    fmaxf(fmaf(acc[m][n][r], inv, bs), 0.f), &orow[n * 16]);
        }
    }
}

extern "C" void kernel_launch(void* const* d_in, const int* in_sizes, int n_in,
                              void* d_out, int out_size, void* d_ws, size_t ws_size,
                              hipStream_t stream) {
    const float* x     = (const float*)d_in[0];
    const float* ow    = (const float*)d_in[1];
    const float* ob    = (const float*)d_in[2];
    const float* cw    = (const float*)d_in[3];
    const float* gamma = (const float*)d_in[4];
    const float* beta  = (const float*)d_in[5];
    const float* mean  = (const float*)d_in[6];
    const float* var   = (const float*)d_in[7];
    float* out = (float*)d_out;

    unsigned short* warped = (unsigned short*)d_ws;                       // 64 MB
    unsigned short* wtb    = (unsigned short*)((char*)d_ws + 67108864);   // 72 KB
    float*          offsb  = (float*)((char*)d_ws + 67108864 + 73728);    // 4.2 MB

    wt_kernel<<<(9 * 64 * 64 + 255) / 256, 256, 0, stream>>>(cw, wtb);

    offset_conv_kernel<<<dim3(2048), 256, 0, stream>>>(x, ow, ob, offsb);

    warp_kernel<<<dim3(1024), 512, 0, stream>>>(x, offsb, warped);

    conv_mfma_kernel<<<dim3(2048), 256, 0, stream>>>(warped, wtb, gamma, beta, mean, var, out);
}